// Round 2
// baseline (697.501 us; speedup 1.0000x reference)
//
#include <hip/hip_runtime.h>
#include <stdint.h>

typedef unsigned short u16;
typedef __attribute__((ext_vector_type(8))) short short8;
typedef __attribute__((ext_vector_type(4))) float f32x4;

static __device__ __forceinline__ float b2f(u16 u) {
    union { unsigned int i; float f; } x; x.i = ((unsigned int)u) << 16; return x.f;
}
static __device__ __forceinline__ u16 f2b(float f) {
    unsigned int x = __builtin_bit_cast(unsigned int, f);
    x += 0x7fffu + ((x >> 16) & 1u);           // RNE
    return (u16)(x >> 16);
}
static __device__ __forceinline__ void async16(const u16* g, u16* l) {
    __builtin_amdgcn_global_load_lds(
        (const __attribute__((address_space(1))) unsigned int*)g,
        (__attribute__((address_space(3))) unsigned int*)l, 16, 0, 0);
}

// ---------- out-of-place GEMM: C = relu(A[M,K] @ Bt[N,K]^T), 128x128 tile ----------
__global__ __launch_bounds__(256, 2) void gemm_oop_k(
    const u16* __restrict__ A, const u16* __restrict__ Bt, u16* __restrict__ C,
    int M, int N, int K, int lda, int ldb, int nbn)
{
    __shared__ u16 lA[128 * 64];
    __shared__ u16 lB[128 * 64];
    const int tid = threadIdx.x;
    const int gid = blockIdx.x;
    const int q = (int)gridDim.x >> 3;               // grid always %8==0
    const int gbi = (gid & 7) * q + (gid >> 3);
    const int mb = gbi / nbn, nb = gbi % nbn;

    const int wid = tid >> 6, lane = tid & 63;
    const int wr = (wid >> 1) * 64, wc = (wid & 1) * 64;
    const int lrow = lane & 15, lko = (lane >> 4) * 8;

    f32x4 acc[4][4] = {};

    const int srow = tid >> 3;           // 0..31
    const int scol = (tid & 7) * 8;      // 0..56
    const u16* ag = A + (size_t)(mb * 128 + srow) * lda + scol;
    const u16* bg = Bt + (size_t)(nb * 128 + srow) * ldb + scol;
    u16* la = &lA[tid * 8];
    u16* lb = &lB[tid * 8];

    for (int k0 = 0; k0 < K; k0 += 64) {
#pragma unroll
        for (int i = 0; i < 4; ++i) {
            async16(ag + (size_t)(i * 32) * lda + k0, la + i * 2048);
            async16(bg + (size_t)(i * 32) * ldb + k0, lb + i * 2048);
        }
        __syncthreads();
#pragma unroll
        for (int kk = 0; kk < 64; kk += 32) {
            short8 af[4], bf[4];
#pragma unroll
            for (int m = 0; m < 4; ++m)
                af[m] = *(const short8*)&lA[(wr + m * 16 + lrow) * 64 + kk + lko];
#pragma unroll
            for (int n = 0; n < 4; ++n)
                bf[n] = *(const short8*)&lB[(wc + n * 16 + lrow) * 64 + kk + lko];
#pragma unroll
            for (int m = 0; m < 4; ++m)
#pragma unroll
                for (int n = 0; n < 4; ++n)
                    acc[m][n] = __builtin_amdgcn_mfma_f32_16x16x32_bf16(af[m], bf[n], acc[m][n], 0, 0, 0);
        }
        __syncthreads();
    }

    const int r0 = mb * 128 + wr + (lane >> 4) * 4;
    const int c0 = nb * 128 + wc + (lane & 15);
#pragma unroll
    for (int m = 0; m < 4; ++m)
#pragma unroll
        for (int n = 0; n < 4; ++n)
#pragma unroll
            for (int r = 0; r < 4; ++r) {
                const size_t idx = (size_t)(r0 + m * 16 + r) * N + c0 + n * 16;
                C[idx] = f2b(fmaxf(acc[m][n][r], 0.f));
            }
}

// -------- in-place message GEMM: msg = relu([f_bonds | amsg[src]-msg[rev]] @ Wcomb^T) ----
// Block owns rows [r0, r0+128) exclusively (e^1 stays in-panel), full N=512 per block:
// all msg reads by this block precede its writes; no cross-block hazard. Deterministic.
// 8 waves (2 row x 4 col), wave tile 64x128, BK=32, K=704 (192 direct + 512 gathered).
__global__ __launch_bounds__(512, 2) void gemm_ip_k(
    const u16* __restrict__ Abonds,   // [131072,192] bf16
    const u16* __restrict__ Wc,       // [512,704] bf16 (Bt layout)
    const u16* __restrict__ amsg,     // [65536,512] bf16
    u16* __restrict__ msg,            // [131072,512] bf16, updated in place
    const int* __restrict__ bsrc)
{
    __shared__ u16 lA[128 * 32];
    __shared__ u16 lB[512 * 32];
    const int t = threadIdx.x;
    const int r0 = blockIdx.x * 128;
    const int wid = t >> 6, lane = t & 63;
    const int wrow = (wid >> 2) * 64, wcol = (wid & 3) * 128;
    const int lrow = lane & 15, lko = (lane >> 4) * 8;

    f32x4 acc[4][8] = {};

    const int arow = t >> 2, acolk = (t & 3) * 8;   // A-stage: row 0..127, k-off 0/8/16/24
    const int e = r0 + arow;
    const u16* agb   = Abonds + (size_t)e * 192 + acolk;
    const u16* amrow = amsg + (size_t)bsrc[e] * 512 + acolk;
    const u16* mrow  = msg + (size_t)(e ^ 1) * 512 + acolk;
    const u16* bg    = Wc + (size_t)(t >> 2) * 704 + acolk;

    for (int k0 = 0; k0 < 704; k0 += 32) {
        if (k0 < 192) {
            async16(agb + k0, &lA[t * 8]);
        } else {
            short8 av = *(const short8*)(amrow + (k0 - 192));
            short8 mv = *(const short8*)(mrow + (k0 - 192));
            short8 ov;
#pragma unroll
            for (int j = 0; j < 8; ++j)
                ov[j] = (short)f2b(b2f((u16)av[j]) - b2f((u16)mv[j]));
            *(short8*)&lA[t * 8] = ov;
        }
#pragma unroll
        for (int i = 0; i < 4; ++i)
            async16(bg + (size_t)(i * 128) * 704 + k0, &lB[i * 4096 + t * 8]);
        __syncthreads();
        short8 af[4], bf[8];
#pragma unroll
        for (int m = 0; m < 4; ++m)
            af[m] = *(const short8*)&lA[(wrow + m * 16 + lrow) * 32 + lko];
#pragma unroll
        for (int n = 0; n < 8; ++n)
            bf[n] = *(const short8*)&lB[(wcol + n * 16 + lrow) * 32 + lko];
#pragma unroll
        for (int m = 0; m < 4; ++m)
#pragma unroll
            for (int n = 0; n < 8; ++n)
                acc[m][n] = __builtin_amdgcn_mfma_f32_16x16x32_bf16(af[m], bf[n], acc[m][n], 0, 0, 0);
        __syncthreads();
    }

    const int rr = r0 + wrow + (lane >> 4) * 4;
    const int cc = wcol + (lane & 15);
#pragma unroll
    for (int m = 0; m < 4; ++m)
#pragma unroll
        for (int n = 0; n < 8; ++n)
#pragma unroll
            for (int r = 0; r < 4; ++r)
                msg[(size_t)(rr + m * 16 + r) * 512 + cc + n * 16] = f2b(fmaxf(acc[m][n][r], 0.f));
}

// -------------- per-molecule segment sum (deterministic, no atomics) ------------------
template<bool FINAL>
__global__ __launch_bounds__(256) void segsum_k(
    const u16* __restrict__ msg, const int* __restrict__ bdst, u16* __restrict__ out)
{
    __shared__ float acc[32][256];
    const int m = blockIdx.x >> 1;
    const int t = threadIdx.x;
    const int c = (blockIdx.x & 1) * 256 + t;
#pragma unroll
    for (int a = 0; a < 32; ++a) acc[a][t] = 0.f;
    const int eb = m * 64;
    for (int ee = 0; ee < 64; ++ee) {
        int d = bdst[eb + ee] & 31;
        acc[d][t] += b2f(msg[(size_t)(eb + ee) * 512 + c]);
    }
#pragma unroll
    for (int a = 0; a < 32; ++a) {
        if constexpr (FINAL)
            out[(size_t)(m * 32 + a) * 704 + 160 + c] = f2b(acc[a][t]);
        else
            out[(size_t)(m * 32 + a) * 512 + c] = f2b(acc[a][t]);
    }
}

// ------------------------------ prep kernels ----------------------------------
__global__ void cast_bonds_k(const float* __restrict__ fb, u16* __restrict__ Ab) {
    const int total = 131072 * 192;
    for (int idx = blockIdx.x * blockDim.x + threadIdx.x; idx < total; idx += gridDim.x * blockDim.x) {
        int b = idx / 192, cc = idx % 192;
        Ab[idx] = f2b((cc < 147) ? fb[(size_t)b * 147 + cc] : 0.f);
    }
}

__global__ void wcomb_k(const float* __restrict__ Wi, const float* __restrict__ Wh, u16* __restrict__ Wc) {
    const int total = 512 * 704;
    for (int idx = blockIdx.x * blockDim.x + threadIdx.x; idx < total; idx += gridDim.x * blockDim.x) {
        int n = idx / 704, k = idx % 704;
        float v = 0.f;
        if (k < 147) v = Wi[(size_t)k * 512 + n];
        else if (k >= 192) v = Wh[(size_t)(k - 192) * 512 + n];
        Wc[idx] = f2b(v);
    }
}

__global__ void wcat_k(const float* __restrict__ Wo, u16* __restrict__ Wt) {
    const int total = 512 * 704;
    for (int idx = blockIdx.x * blockDim.x + threadIdx.x; idx < total; idx += gridDim.x * blockDim.x) {
        int n = idx / 704, k = idx % 704;
        float v = 0.f;
        if (k < 133) v = Wo[(size_t)k * 512 + n];
        else if (k >= 160 && k < 672) v = Wo[(size_t)(k - 27) * 512 + n];
        Wt[idx] = f2b(v);
    }
}

__global__ void wtrans_k(const float* __restrict__ W, u16* __restrict__ Wt) {
    const int total = 512 * 512;
    for (int idx = blockIdx.x * blockDim.x + threadIdx.x; idx < total; idx += gridDim.x * blockDim.x) {
        int n = idx / 512, k = idx % 512;
        Wt[idx] = f2b(W[(size_t)k * 512 + n]);
    }
}

__global__ void cat_prep_k(const float* __restrict__ f_atoms, u16* __restrict__ Acat) {
    const int total = 65536 * 192;
    for (int idx = blockIdx.x * blockDim.x + threadIdx.x; idx < total; idx += gridDim.x * blockDim.x) {
        int a = idx / 192, j = idx % 192;
        int col = (j < 160) ? j : (512 + j);            // cols 0..159 and 672..703
        float v = (col < 133) ? f_atoms[(size_t)a * 133 + col] : 0.f;
        Acat[(size_t)a * 704 + col] = f2b(v);
    }
}

__global__ void mol_mean_k(const u16* __restrict__ ah, u16* __restrict__ mv) {
    const int m = blockIdx.x, t = threadIdx.x;
#pragma unroll
    for (int h = 0; h < 2; ++h) {
        int c = h * 256 + t;
        float s = 0.f;
        for (int a = 0; a < 32; ++a) s += b2f(ah[(size_t)(m * 32 + a) * 512 + c]);
        mv[(size_t)m * 512 + c] = f2b(s * 0.03125f);
    }
}

__global__ void logits_k(const u16* __restrict__ h, const float* __restrict__ ow,
                         const float* __restrict__ ob, float* __restrict__ out) {
    const int row = blockIdx.x * 4 + (threadIdx.x >> 6);
    const int lane = threadIdx.x & 63;
    const u16* hr = h + (size_t)row * 512 + lane * 8;
    float s = 0.f;
#pragma unroll
    for (int j = 0; j < 8; ++j) s += b2f(hr[j]) * ow[lane * 8 + j];
#pragma unroll
    for (int o = 32; o > 0; o >>= 1) s += __shfl_down(s, o);
    if (lane == 0) out[row] = s + ob[0];
}

// ------------------------------- launch ---------------------------------------
extern "C" void kernel_launch(void* const* d_in, const int* in_sizes, int n_in,
                              void* d_out, int out_size, void* d_ws, size_t ws_size,
                              hipStream_t stream) {
    const float* f_atoms = (const float*)d_in[0];
    const float* f_bonds = (const float*)d_in[1];
    const float* W_i  = (const float*)d_in[2];
    const float* W_h  = (const float*)d_in[3];
    const float* W_o  = (const float*)d_in[4];
    const float* c1W  = (const float*)d_in[5];
    const float* c2W  = (const float*)d_in[7];
    const float* c3W  = (const float*)d_in[9];
    const float* outW = (const float*)d_in[11];
    const float* outB = (const float*)d_in[12];
    const int* bsrc = (const int*)d_in[13];
    const int* bdst = (const int*)d_in[14];
    float* out = (float*)d_out;
    (void)in_sizes; (void)n_in; (void)out_size;

    // budget: 134217728 + 67108864 + 50331648 + 2*720896 + 3*524288 = 254,672,896 B
    if (ws_size < 254672896u) return;   // diagnostic: absmax-fail instead of OOB crash

    char* w = (char*)d_ws;
    size_t off = 0;
    auto alloc = [&](size_t bytes) {
        size_t o = (off + 255) & ~(size_t)255; off = o + bytes; return (void*)(w + o);
    };

    u16* msg    = (u16*)alloc(134217728);   // [131072,512]
    u16* amsg   = (u16*)alloc(67108864);    // [65536,512]
    u16* Abonds = (u16*)alloc(50331648);    // [131072,192]
    u16* Wcomb  = (u16*)alloc(720896);      // [512,704]  = [W_i;0;W_h]^T
    u16* WcT    = (u16*)alloc(720896);      // [512,704]  = W_o^T remapped
    u16* c1T    = (u16*)alloc(524288);
    u16* c2T    = (u16*)alloc(524288);
    u16* c3T    = (u16*)alloc(524288);
    // aliases over dead regions:
    u16* Acat  = amsg;                 // [65536,704] spans amsg+Abonds (both dead by then)
    u16* atomh = msg;                  // [65536,512] in dead msg
    u16* molv  = msg + 33554432;       // byte offset 64MB within msg
    u16* h1    = molv + 1048576;
    u16* h2    = h1 + 1048576;
    u16* h3    = h2 + 1048576;

    // prep
    cast_bonds_k<<<4096, 256, 0, stream>>>(f_bonds, Abonds);
    wcomb_k<<<512, 256, 0, stream>>>(W_i, W_h, Wcomb);
    wcat_k<<<512, 256, 0, stream>>>(W_o, WcT);
    wtrans_k<<<512, 256, 0, stream>>>(c1W, c1T);
    wtrans_k<<<512, 256, 0, stream>>>(c2W, c2T);
    wtrans_k<<<512, 256, 0, stream>>>(c3W, c3T);

    // msg0 = relu(f_bonds @ W_i)   (Wcomb rows 147..191 are zero, A pad cols too)
    gemm_oop_k<<<4096, 256, 0, stream>>>(Abonds, Wcomb, msg, 131072, 512, 192, 192, 704, 4);

    for (int it = 0; it < 2; ++it) {
        segsum_k<false><<<4096, 256, 0, stream>>>(msg, bdst, amsg);
        gemm_ip_k<<<1024, 512, 0, stream>>>(Abonds, Wcomb, amsg, msg, bsrc);
    }

    // Acat: static cols (after amsg/Abonds dead), then final segment sum into cols 160..671
    cat_prep_k<<<4096, 256, 0, stream>>>(f_atoms, Acat);
    segsum_k<true><<<4096, 256, 0, stream>>>(msg, bdst, Acat);

    // atom_h = relu(Acat @ W_o)
    gemm_oop_k<<<2048, 256, 0, stream>>>(Acat, WcT, atomh, 65536, 512, 704, 704, 704, 4);
    mol_mean_k<<<2048, 256, 0, stream>>>(atomh, molv);

    // classifier
    gemm_oop_k<<<64, 256, 0, stream>>>(molv, c1T, h1, 2048, 512, 512, 512, 512, 4);
    gemm_oop_k<<<64, 256, 0, stream>>>(h1, c2T, h2, 2048, 512, 512, 512, 512, 4);
    gemm_oop_k<<<64, 256, 0, stream>>>(h2, c3T, h3, 2048, 512, 512, 512, 512, 4);
    logits_k<<<512, 256, 0, stream>>>(h3, outW, outB, out);
}